// Round 8
// baseline (390.740 us; speedup 1.0000x reference)
//
#include <hip/hip_runtime.h>
#include <math.h>

// Problem constants (from reference setup_inputs)
constexpr int N    = 50000;   // nodes
constexpr int E    = 800000;  // edges
constexpr int CIN  = 100;     // input channels
constexpr int CH   = 128;     // hidden channels
constexpr int COUT = 47;      // output channels
constexpr int NOUT = 25000;   // original_size (rows emitted)
constexpr int CP   = 48;      // COUT padded (alignment / lane mapping)
constexpr int NB   = (N + 255) / 256;   // 196 scan blocks

// ---------------------------------------------------------------------------
// CSR build stage 1: in-degree histogram (int atomics, low contention)
__global__ void hist_kernel(const int* __restrict__ dst, int* __restrict__ cnt) {
    int i = blockIdx.x * blockDim.x + threadIdx.x;
    if (i < E) atomicAdd(&cnt[dst[i]], 1);
}

// CSR build stage 2a: per-block exclusive scan of cnt (coalesced, parallel)
__global__ __launch_bounds__(256) void scan_blocks(const int* __restrict__ cnt,
        int* __restrict__ row_ptr, int* __restrict__ blkSum) {
    __shared__ int s[256];
    int t = threadIdx.x;
    int i = blockIdx.x * 256 + t;
    int v = (i < N) ? cnt[i] : 0;
    s[t] = v;
    __syncthreads();
    for (int off = 1; off < 256; off <<= 1) {
        int a = s[t];
        int u = (t >= off) ? s[t - off] : 0;
        __syncthreads();
        s[t] = a + u;
        __syncthreads();
    }
    if (i < N) row_ptr[i] = s[t] - v;          // local exclusive prefix
    if (t == 255) blkSum[blockIdx.x] = s[255]; // block total
}

// CSR build stage 2b: scan the 196 block sums (single tiny block)
__global__ __launch_bounds__(256) void scan_sums(int* __restrict__ blkSum,
        int* __restrict__ blkOff) {
    __shared__ int s[256];
    int t = threadIdx.x;
    int v = (t < NB) ? blkSum[t] : 0;
    s[t] = v;
    __syncthreads();
    for (int off = 1; off < 256; off <<= 1) {
        int a = s[t];
        int u = (t >= off) ? s[t - off] : 0;
        __syncthreads();
        s[t] = a + u;
        __syncthreads();
    }
    if (t < NB) blkOff[t] = s[t] - v;          // exclusive offsets
}

// CSR build stage 2c: apply block offsets; produce cursor copy; row_ptr[N]=E
__global__ __launch_bounds__(256) void scan_add(int* __restrict__ row_ptr,
        int* __restrict__ cursor, const int* __restrict__ blkOff) {
    int i = blockIdx.x * 256 + threadIdx.x;
    if (i < N) {
        int v = row_ptr[i] + blkOff[blockIdx.x];
        row_ptr[i] = v;
        cursor[i]  = v;
        if (i == N - 1) row_ptr[N] = E;
    }
}

// CSR build stage 3: bucket-fill edge sources (int atomics on cursors)
__global__ void fill_kernel(const int* __restrict__ src, const int* __restrict__ dst,
        int* __restrict__ cursor, int* __restrict__ col) {
    int i = blockIdx.x * blockDim.x + threadIdx.x;
    if (i < E) {
        int d = dst[i];
        int p = atomicAdd(&cursor[d], 1);
        col[p] = src[i];
    }
}

// Pad layer-2 weights to 48 columns (col 47 = 0); zero-padded bias.
__global__ __launch_bounds__(256) void pad_w2(const float* __restrict__ w2l,
        const float* __restrict__ w2r, const float* __restrict__ b2l,
        float* __restrict__ w2lp, float* __restrict__ w2rp, float* __restrict__ b2p) {
    int i = blockIdx.x * 256 + threadIdx.x;
    if (i < CH * CP) {
        int k = i / CP, c = i - k * CP;
        w2lp[i] = (c < COUT) ? w2l[k * COUT + c] : 0.0f;
        w2rp[i] = (c < COUT) ? w2r[k * COUT + c] : 0.0f;
    }
    if (i < CP) b2p[i] = (i < COUT) ? b2l[i] : 0.0f;
}

// ---------------------------------------------------------------------------
// gather1: agg1[n] = mean_{s in N(n)} x[s]   (row-major [N][CIN], no atomics)
__global__ __launch_bounds__(128) void gather1_kernel(const float* __restrict__ x,
        const int* __restrict__ row_ptr, const int* __restrict__ col,
        float* __restrict__ agg1) {
    int f = threadIdx.x;
    int base = blockIdx.x * 8;
    if (f >= CIN) return;
    for (int r = 0; r < 8; ++r) {
        int n = base + r;
        int b = row_ptr[n], e = row_ptr[n + 1];
        float inv = 1.0f / (float)max(e - b, 1);
        float a0 = 0.f, a1 = 0.f, a2 = 0.f, a3 = 0.f;
        int j = b;
        for (; j + 3 < e; j += 4) {
            int s0 = col[j], s1 = col[j + 1], s2 = col[j + 2], s3 = col[j + 3];
            a0 += x[s0 * CIN + f];
            a1 += x[s1 * CIN + f];
            a2 += x[s2 * CIN + f];
            a3 += x[s3 * CIN + f];
        }
        for (; j < e; ++j) a0 += x[col[j] * CIN + f];
        agg1[n * CIN + f] = ((a0 + a1) + (a2 + a3)) * inv;
    }
}

// ---------------------------------------------------------------------------
// R8 gemm1: weights-in-registers. R7 post-mortem: k-loop stalled on per-k
// scalar weight loads (~200cyc each, shallow SGPR prefetch) -> VALUBusy 22%.
// Inversion: weights are REUSED per node -> preload into VGPRs once per wave
// (lane = channel, 100+100 regs); features are used ONCE -> stream via
// uniform s_loads (consecutive k -> compiler merges to s_load_dwordx16).
// 2-node interleave hides the 4-cyc FMA dep chain. No LDS, no barriers.
// Wave w (of 2048): half = w&1 -> channels half*64+lane; node pairs
// (n, n+1), n/2 = (w>>1) + 1024*i  -> exact cover of N=50000.
__global__ __launch_bounds__(256, 2) void gemm1_reg(
        const float* __restrict__ agg1, const float* __restrict__ x,
        const float* __restrict__ w1l, const float* __restrict__ b1l,
        const float* __restrict__ w1r, float* __restrict__ h) {
    int t = threadIdx.x;
    int c = t & 63;
    int wv = __builtin_amdgcn_readfirstlane(t >> 6);   // 0..3, provably uniform
    int w = blockIdx.x * 4 + wv;                       // 0..2047
    int ch = (w & 1) * 64 + c;
    int stream = w >> 1;                               // 0..1023
    float wl[CIN], wr[CIN];
    #pragma unroll
    for (int k = 0; k < CIN; ++k) wl[k] = w1l[k * CH + ch];   // coalesced, once
    #pragma unroll
    for (int k = 0; k < CIN; ++k) wr[k] = w1r[k * CH + ch];
    float bias = b1l[ch];
    for (int n = stream * 2; n < N; n += 2048) {
        const float* A0 = agg1 + (size_t)n * CIN;      // n uniform -> s_load
        const float* A1 = A0 + CIN;
        const float* X0 = x + (size_t)n * CIN;
        const float* X1 = X0 + CIN;
        float a0 = bias, a1 = bias;
        #pragma unroll
        for (int k = 0; k < CIN; ++k) {
            a0 = fmaf(A0[k], wl[k], a0);
            a1 = fmaf(A1[k], wl[k], a1);
            a0 = fmaf(X0[k], wr[k], a0);
            a1 = fmaf(X1[k], wr[k], a1);
        }
        h[(size_t)n * CH + ch] = a0;                   // 256B coalesced per wave
        h[(size_t)(n + 1) * CH + ch] = a1;
    }
}

// R8 gemm2: same inversion. Wave w of 3072: w<2048 -> gsrc = h@w2lp over all N
// (pairs: n/2 = w + 2048*i); else -> gself = h@w2rp + b2p over NOUT
// (pairs: n/2 = (w-2048) + 1024*i). lane c<48 holds the weight column.
__global__ __launch_bounds__(256, 2) void gemm2_reg(
        const float* __restrict__ h, const float* __restrict__ w2lp,
        const float* __restrict__ b2p, const float* __restrict__ w2rp,
        float* __restrict__ gsrc, float* __restrict__ gself) {
    int t = threadIdx.x;
    int c = t & 63;
    int wv = __builtin_amdgcn_readfirstlane(t >> 6);
    int w = blockIdx.x * 4 + wv;                       // 0..3071
    bool self = (w >= 2048);
    bool lane_ok = (c < CP);
    const float* W = self ? w2rp : w2lp;
    float wreg[CH];
    #pragma unroll
    for (int k = 0; k < CH; ++k) wreg[k] = lane_ok ? W[k * CP + c] : 0.0f;
    float bias = (self && lane_ok) ? b2p[c] : 0.0f;
    float* G = self ? gself : gsrc;
    int stream = self ? (w - 2048) : w;
    int step = self ? 2048 : 4096;
    int limit = self ? NOUT : N;
    for (int n = stream * 2; n < limit; n += step) {
        const float* H0 = h + (size_t)n * CH;          // n uniform -> s_load
        const float* H1 = H0 + CH;
        float a0 = bias, a1 = bias;
        #pragma unroll
        for (int k = 0; k < CH; ++k) {
            a0 = fmaf(H0[k], wreg[k], a0);
            a1 = fmaf(H1[k], wreg[k], a1);
        }
        if (lane_ok) {
            G[(size_t)n * CP + c] = a0;                // 192B coalesced
            G[(size_t)(n + 1) * CP + c] = a1;
        }
    }
}

// ---------------------------------------------------------------------------
// final: out[n] = log_softmax( mean_{s in N(n)} gsrc[s] + gself[n] )
// One wave per output node; lanes own channels; 192B-row gathers.
__global__ __launch_bounds__(64) void final_kernel(const float* __restrict__ gsrc,
        const float* __restrict__ gself, const int* __restrict__ row_ptr,
        const int* __restrict__ col, float* __restrict__ out) {
    int n = blockIdx.x;
    int c = threadIdx.x;
    int b = row_ptr[n], e = row_ptr[n + 1];
    float inv = 1.0f / (float)max(e - b, 1);
    float a0 = 0.f, a1 = 0.f;
    if (c < CP) {
        int j = b;
        for (; j + 1 < e; j += 2) {
            a0 += gsrc[(size_t)col[j] * CP + c];
            a1 += gsrc[(size_t)col[j + 1] * CP + c];
        }
        if (j < e) a0 += gsrc[(size_t)col[j] * CP + c];
    }
    float val = (c < COUT) ? ((a0 + a1) * inv + gself[(size_t)n * CP + c]) : -INFINITY;
    float m = val;
    #pragma unroll
    for (int off = 32; off > 0; off >>= 1) m = fmaxf(m, __shfl_xor(m, off, 64));
    float ex = (c < COUT) ? expf(val - m) : 0.f;
    float ssum = ex;
    #pragma unroll
    for (int off = 32; off > 0; off >>= 1) ssum += __shfl_xor(ssum, off, 64);
    if (c < COUT) out[(size_t)n * COUT + c] = val - m - logf(ssum);
}

// ---------------------------------------------------------------------------
extern "C" void kernel_launch(void* const* d_in, const int* in_sizes, int n_in,
                              void* d_out, int out_size, void* d_ws, size_t ws_size,
                              hipStream_t stream) {
    const float* x   = (const float*)d_in[0];
    const int*   ei  = (const int*)d_in[1];   // [2, E]: row 0 = src, row 1 = dst
    const int*   src = ei;
    const int*   dst = ei + E;
    const float* w1l = (const float*)d_in[3];
    const float* b1l = (const float*)d_in[4];
    const float* w1r = (const float*)d_in[5];
    const float* w2l = (const float*)d_in[6];
    const float* b2l = (const float*)d_in[7];
    const float* w2r = (const float*)d_in[8];
    float* out = (float*)d_out;

    // ws: ints [cnt N | row_ptr N+1 | cursor N | blkSum NB | blkOff NB | col E]
    // floats [agg1 N*CIN (aliased later: gsrc N*CP + gself NOUT*CP)] [h N*CH]
    //        [w2lp CH*CP | w2rp CH*CP | b2p CP]
    // agg1 dead after gemm1_reg; gemm2_reg reads only h -> alias is safe.
    int* cnt     = (int*)d_ws;
    int* row_ptr = cnt + N;
    int* cursor  = row_ptr + N + 1;
    int* blkSum  = cursor + N;
    int* blkOff  = blkSum + NB;
    int* col     = blkOff + NB;
    size_t intWords = (size_t)N + (N + 1) + N + NB + NB + E;
    intWords = (intWords + 3) & ~(size_t)3;
    float* agg1  = (float*)d_ws + intWords;
    float* gsrc  = agg1;                          // alias (9.6MB+4.8MB <= 20MB)
    float* gself = gsrc + (size_t)N * CP;
    float* h     = agg1 + (size_t)N * CIN;
    float* w2lp  = h + (size_t)N * CH;
    float* w2rp  = w2lp + CH * CP;
    float* b2p   = w2rp + CH * CP;
    // total ws ~48.9 MB (< 58.6 MB proven available)

    hipMemsetAsync(cnt, 0, (size_t)N * sizeof(int), stream);
    pad_w2      <<<(CH * CP + 255) / 256, 256, 0, stream>>>(w2l, w2r, b2l, w2lp, w2rp, b2p);
    hist_kernel <<<(E + 255) / 256, 256, 0, stream>>>(dst, cnt);
    scan_blocks <<<NB, 256, 0, stream>>>(cnt, row_ptr, blkSum);
    scan_sums   <<<1, 256, 0, stream>>>(blkSum, blkOff);
    scan_add    <<<NB, 256, 0, stream>>>(row_ptr, cursor, blkOff);
    fill_kernel <<<(E + 255) / 256, 256, 0, stream>>>(src, dst, cursor, col);
    gather1_kernel<<<N / 8, 128, 0, stream>>>(x, row_ptr, col, agg1);
    gemm1_reg   <<<512, 256, 0, stream>>>(agg1, x, w1l, b1l, w1r, h);
    gemm2_reg   <<<768, 256, 0, stream>>>(h, w2lp, b2p, w2rp, gsrc, gself);
    final_kernel<<<NOUT, 64, 0, stream>>>(gsrc, gself, row_ptr, col, out);
}

// Round 9
// 364.652 us; speedup vs baseline: 1.0715x; 1.0715x over previous
//
#include <hip/hip_runtime.h>
#include <math.h>

// Problem constants (from reference setup_inputs)
constexpr int N    = 50000;   // nodes
constexpr int E    = 800000;  // edges
constexpr int CIN  = 100;     // input channels
constexpr int CH   = 128;     // hidden channels
constexpr int COUT = 47;      // output channels
constexpr int NOUT = 25000;   // original_size (rows emitted)
constexpr int CP   = 48;      // COUT padded
constexpr int NB   = (N + 255) / 256;   // 196 scan blocks
constexpr int KC1  = 50;      // stage-1 k-chunk
constexpr int KC2  = 64;      // stage-2 k-chunk
constexpr int PADB = (CH * CP + 255) / 256;  // 24 pad blocks appended to scan_blocks

// ---------------------------------------------------------------------------
// CSR stage 1: in-degree histogram
__global__ void hist_kernel(const int* __restrict__ dst, int* __restrict__ cnt) {
    int i = blockIdx.x * blockDim.x + threadIdx.x;
    if (i < E) atomicAdd(&cnt[dst[i]], 1);
}

// CSR stage 2a: per-block exclusive scan of cnt. Blocks >= NB instead pad the
// layer-2 weights to 48 columns (folded here to save a launch).
__global__ __launch_bounds__(256) void scan_blocks(const int* __restrict__ cnt,
        int* __restrict__ row_ptr, int* __restrict__ blkSum,
        const float* __restrict__ w2l, const float* __restrict__ w2r,
        const float* __restrict__ b2l, float* __restrict__ w2lp,
        float* __restrict__ w2rp, float* __restrict__ b2p) {
    int t = threadIdx.x;
    if (blockIdx.x < NB) {
        __shared__ int s[256];
        int i = blockIdx.x * 256 + t;
        int v = (i < N) ? cnt[i] : 0;
        s[t] = v;
        __syncthreads();
        for (int off = 1; off < 256; off <<= 1) {
            int a = s[t];
            int u = (t >= off) ? s[t - off] : 0;
            __syncthreads();
            s[t] = a + u;
            __syncthreads();
        }
        if (i < N) row_ptr[i] = s[t] - v;
        if (t == 255) blkSum[blockIdx.x] = s[255];
    } else {
        int j = (blockIdx.x - NB) * 256 + t;
        if (j < CH * CP) {
            int k = j / CP, c = j - k * CP;
            w2lp[j] = (c < COUT) ? w2l[k * COUT + c] : 0.0f;
            w2rp[j] = (c < COUT) ? w2r[k * COUT + c] : 0.0f;
        }
        if (j < CP) b2p[j] = (j < COUT) ? b2l[j] : 0.0f;
    }
}

// CSR stage 2b: each block reduces blkSum[0..bid) itself (196 ints — cheap),
// then applies the offset. Merges old scan_sums+scan_add into one launch.
__global__ __launch_bounds__(256) void scan_apply(int* __restrict__ row_ptr,
        int* __restrict__ cursor, const int* __restrict__ blkSum) {
    __shared__ int s[256];
    int t = threadIdx.x, bid = blockIdx.x;
    int a = 0;
    for (int j = t; j < bid; j += 256) a += blkSum[j];
    s[t] = a;
    __syncthreads();
    for (int off = 128; off > 0; off >>= 1) {
        if (t < off) s[t] += s[t + off];
        __syncthreads();
    }
    int offset = s[0];
    int i = bid * 256 + t;
    if (i < N) {
        int v = row_ptr[i] + offset;
        row_ptr[i] = v;
        cursor[i]  = v;
        if (i == N - 1) row_ptr[N] = E;
    }
}

// CSR stage 3: bucket-fill edge sources
__global__ void fill_kernel(const int* __restrict__ src, const int* __restrict__ dst,
        int* __restrict__ cursor, int* __restrict__ col) {
    int i = blockIdx.x * blockDim.x + threadIdx.x;
    if (i < E) {
        int d = dst[i];
        int p = atomicAdd(&cursor[d], 1);
        col[p] = src[i];
    }
}

// ---------------------------------------------------------------------------
// gather1: agg1[n] = mean_{s in N(n)} x[s]
__global__ __launch_bounds__(128) void gather1_kernel(const float* __restrict__ x,
        const int* __restrict__ row_ptr, const int* __restrict__ col,
        float* __restrict__ agg1) {
    int f = threadIdx.x;
    int base = blockIdx.x * 8;
    if (f >= CIN) return;
    for (int r = 0; r < 8; ++r) {
        int n = base + r;
        int b = row_ptr[n], e = row_ptr[n + 1];
        float inv = 1.0f / (float)max(e - b, 1);
        float a0 = 0.f, a1 = 0.f, a2 = 0.f, a3 = 0.f;
        int j = b;
        for (; j + 3 < e; j += 4) {
            int s0 = col[j], s1 = col[j + 1], s2 = col[j + 2], s3 = col[j + 3];
            a0 += x[s0 * CIN + f];
            a1 += x[s1 * CIN + f];
            a2 += x[s2 * CIN + f];
            a3 += x[s3 * CIN + f];
        }
        for (; j < e; ++j) a0 += x[col[j] * CIN + f];
        agg1[n * CIN + f] = ((a0 + a1) + (a2 + a3)) * inv;
    }
}

// ---------------------------------------------------------------------------
// R9 fused gemm, fully LDS-resident k-loops. Post-mortems R3/R7/R8: every
// variant whose k-loop touched global/scalar memory stalled at ~200cyc
// latency (VALUBusy 9-31%). Here BOTH operands come from LDS:
//   stage1: h = agg1@w1l + x@w1r + b1l   (2 phases x 2 k-chunks of 50)
//     fbuf[64][51] per-lane (stride 51 -> 2-way, free), wbuf[50][128]
//     broadcast reads; lane=node, wave wv owns 16 channels; acc[16] regs.
//   h -> hbuf[64][129] in LDS (aliases dead fbuf; never touches HBM).
//   stage2: waves 0-3: gsrc = h@w2lp (12 ch each); waves 4-7: gself =
//     h@w2rp + b2p (skip compute when base>=NOUT, still hit barriers).
// LDS = 33024B (hbuf) + 25600B (wbuf) = 58.6KB -> 2 blocks/CU, 16 waves/CU.
// NOTE: gsrc/gself must NOT alias agg1 (other blocks still read agg1).
__global__ __launch_bounds__(512) void fused_gemm(
        const float* __restrict__ agg1, const float* __restrict__ x,
        const float* __restrict__ w1l, const float* __restrict__ b1l,
        const float* __restrict__ w1r,
        const float* __restrict__ w2lp, const float* __restrict__ b2p,
        const float* __restrict__ w2rp,
        float* __restrict__ gsrc, float* __restrict__ gself) {
    __shared__ float lds[64 * 129 + KC1 * CH];   // [hbuf|fbuf-alias][wbuf]
    float* hbuf = lds;                 // stride 129
    float* fbuf = lds;                 // stride 51, dead before hbuf written
    float* wbuf = lds + 64 * 129;      // 6400 floats

    int t = threadIdx.x;
    int base = blockIdx.x * 64;
    int lane = t & 63;                 // node within tile
    int wv = __builtin_amdgcn_readfirstlane(t >> 6);   // 0..7
    int c0 = wv * 16;                  // stage-1 channel base (uniform)
    int nmax = N - 1 - base; if (nmax > 63) nmax = 63;  // clamp for partial tile

    float acc[16];
    #pragma unroll
    for (int c = 0; c < 16; ++c) acc[c] = b1l[c0 + c];

    // ---- stage 1: two phases (mean, self), k-chunks of 50, all-LDS k-loop
    for (int ph = 0; ph < 2; ++ph) {
        const float* F = ph ? x : agg1;
        const float* W = ph ? w1r : w1l;
        for (int k0 = 0; k0 < CIN; k0 += KC1) {
            for (int i = t; i < 64 * KC1; i += 512) {
                int row = i / KC1, k = i - row * KC1;
                int rr = row <= nmax ? row : nmax;
                fbuf[row * (KC1 + 1) + k] = F[(size_t)(base + rr) * CIN + k0 + k];
            }
            for (int i = t; i < KC1 * CH; i += 512)
                wbuf[i] = W[k0 * CH + i];              // contiguous rows
            __syncthreads();
            const float* frow = fbuf + lane * (KC1 + 1);
            for (int k = 0; k < KC1; ++k) {
                float fv = frow[k];
                const float* wr = wbuf + k * CH + c0;  // broadcast
                #pragma unroll
                for (int c = 0; c < 16; ++c) acc[c] = fmaf(fv, wr[c], acc[c]);
            }
            __syncthreads();
        }
    }
    // spill h tile to LDS (fbuf dead; barrier above guarantees reads done)
    #pragma unroll
    for (int c = 0; c < 16; ++c) hbuf[lane * 129 + c0 + c] = acc[c];
    __syncthreads();

    // ---- stage 2: gsrc/gself from hbuf, w2 slabs staged per k-chunk
    bool isSelf = (wv >= 4);
    bool active = !isSelf || (base < NOUT);
    int d0 = (wv & 3) * 12;            // uniform (wv is readfirstlane-derived)
    float a2[12];
    #pragma unroll
    for (int c = 0; c < 12; ++c) a2[c] = isSelf ? b2p[d0 + c] : 0.0f;
    for (int k0 = 0; k0 < CH; k0 += KC2) {
        for (int i = t; i < 2 * KC2 * CP; i += 512)    // 6144 floats: [l | r]
            wbuf[i] = (i < KC2 * CP) ? w2lp[k0 * CP + i]
                                     : w2rp[k0 * CP + (i - KC2 * CP)];
        __syncthreads();
        if (active) {
            const float* hrow = hbuf + lane * 129 + k0;
            const float* wb = wbuf + (isSelf ? KC2 * CP : 0) + d0;
            for (int k = 0; k < KC2; ++k) {
                float fv = hrow[k];
                const float* wr = wb + k * CP;         // broadcast
                #pragma unroll
                for (int c = 0; c < 12; ++c) a2[c] = fmaf(fv, wr[c], a2[c]);
            }
        }
        __syncthreads();
    }
    int n = base + lane;
    if (isSelf) {
        if (n < NOUT) {
            #pragma unroll
            for (int c = 0; c < 12; ++c) gself[(size_t)n * CP + d0 + c] = a2[c];
        }
    } else {
        if (n < N) {
            #pragma unroll
            for (int c = 0; c < 12; ++c) gsrc[(size_t)n * CP + d0 + c] = a2[c];
        }
    }
}

// ---------------------------------------------------------------------------
// final: out[n] = log_softmax( mean_{s in N(n)} gsrc[s] + gself[n] )
__global__ __launch_bounds__(64) void final_kernel(const float* __restrict__ gsrc,
        const float* __restrict__ gself, const int* __restrict__ row_ptr,
        const int* __restrict__ col, float* __restrict__ out) {
    int n = blockIdx.x;
    int c = threadIdx.x;
    int b = row_ptr[n], e = row_ptr[n + 1];
    float inv = 1.0f / (float)max(e - b, 1);
    float a0 = 0.f, a1 = 0.f;
    if (c < CP) {
        int j = b;
        for (; j + 1 < e; j += 2) {
            a0 += gsrc[(size_t)col[j] * CP + c];
            a1 += gsrc[(size_t)col[j + 1] * CP + c];
        }
        if (j < e) a0 += gsrc[(size_t)col[j] * CP + c];
    }
    float val = (c < COUT) ? ((a0 + a1) * inv + gself[(size_t)n * CP + c]) : -INFINITY;
    float m = val;
    #pragma unroll
    for (int off = 32; off > 0; off >>= 1) m = fmaxf(m, __shfl_xor(m, off, 64));
    float ex = (c < COUT) ? expf(val - m) : 0.f;
    float ssum = ex;
    #pragma unroll
    for (int off = 32; off > 0; off >>= 1) ssum += __shfl_xor(ssum, off, 64);
    if (c < COUT) out[(size_t)n * COUT + c] = val - m - logf(ssum);
}

// ---------------------------------------------------------------------------
extern "C" void kernel_launch(void* const* d_in, const int* in_sizes, int n_in,
                              void* d_out, int out_size, void* d_ws, size_t ws_size,
                              hipStream_t stream) {
    const float* x   = (const float*)d_in[0];
    const int*   ei  = (const int*)d_in[1];   // [2, E]: row 0 = src, row 1 = dst
    const int*   src = ei;
    const int*   dst = ei + E;
    const float* w1l = (const float*)d_in[3];
    const float* b1l = (const float*)d_in[4];
    const float* w1r = (const float*)d_in[5];
    const float* w2l = (const float*)d_in[6];
    const float* b2l = (const float*)d_in[7];
    const float* w2r = (const float*)d_in[8];
    float* out = (float*)d_out;

    // ws: ints [cnt N | row_ptr N+1 | cursor N | blkSum NB | col E]
    // floats [agg1 N*CIN | gsrc N*CP | gself NOUT*CP | w2lp | w2rp | b2p]
    // NO aliasing: fused_gemm reads agg1 while writing gsrc across blocks.
    int* cnt     = (int*)d_ws;
    int* row_ptr = cnt + N;
    int* cursor  = row_ptr + N + 1;
    int* blkSum  = cursor + N;
    int* col     = blkSum + NB;
    size_t intWords = (size_t)N + (N + 1) + N + NB + E;
    intWords = (intWords + 3) & ~(size_t)3;
    float* agg1  = (float*)d_ws + intWords;
    float* gsrc  = agg1 + (size_t)N * CIN;
    float* gself = gsrc + (size_t)N * CP;
    float* w2lp  = gself + (size_t)NOUT * CP;
    float* w2rp  = w2lp + CH * CP;
    float* b2p   = w2rp + CH * CP;
    // total ws ~38.3 MB (< 58.6 MB proven available)

    hipMemsetAsync(cnt, 0, (size_t)N * sizeof(int), stream);
    hist_kernel <<<(E + 255) / 256, 256, 0, stream>>>(dst, cnt);
    scan_blocks <<<NB + PADB, 256, 0, stream>>>(cnt, row_ptr, blkSum,
                                                w2l, w2r, b2l, w2lp, w2rp, b2p);
    scan_apply  <<<NB, 256, 0, stream>>>(row_ptr, cursor, blkSum);
    fill_kernel <<<(E + 255) / 256, 256, 0, stream>>>(src, dst, cursor, col);
    gather1_kernel<<<N / 8, 128, 0, stream>>>(x, row_ptr, col, agg1);
    fused_gemm  <<<(N + 63) / 64, 512, 0, stream>>>(agg1, x, w1l, b1l, w1r,
                                                    w2lp, b2p, w2rp, gsrc, gself);
    final_kernel<<<NOUT, 64, 0, stream>>>(gsrc, gself, row_ptr, col, out);
}

// Round 10
// 349.699 us; speedup vs baseline: 1.1174x; 1.0428x over previous
//
#include <hip/hip_runtime.h>
#include <math.h>

// Problem constants (from reference setup_inputs)
constexpr int N    = 50000;   // nodes
constexpr int E    = 800000;  // edges
constexpr int CIN  = 100;     // input channels
constexpr int CH   = 128;     // hidden channels
constexpr int COUT = 47;      // output channels
constexpr int NOUT = 25000;   // original_size (rows emitted)
constexpr int CP   = 48;      // COUT padded
constexpr int NB   = (N + 255) / 256;   // 196 scan blocks
constexpr int PADB = (CH * CP + 255) / 256;  // 24 pad blocks appended to scan_blocks

// ---------------------------------------------------------------------------
// CSR stage 1: in-degree histogram
__global__ void hist_kernel(const int* __restrict__ dst, int* __restrict__ cnt) {
    int i = blockIdx.x * blockDim.x + threadIdx.x;
    if (i < E) atomicAdd(&cnt[dst[i]], 1);
}

// CSR stage 2a: per-block exclusive scan of cnt; extra blocks pad w2 to 48 cols.
__global__ __launch_bounds__(256) void scan_blocks(const int* __restrict__ cnt,
        int* __restrict__ row_ptr, int* __restrict__ blkSum,
        const float* __restrict__ w2l, const float* __restrict__ w2r,
        const float* __restrict__ b2l, float* __restrict__ w2lp,
        float* __restrict__ w2rp, float* __restrict__ b2p) {
    int t = threadIdx.x;
    if (blockIdx.x < NB) {
        __shared__ int s[256];
        int i = blockIdx.x * 256 + t;
        int v = (i < N) ? cnt[i] : 0;
        s[t] = v;
        __syncthreads();
        for (int off = 1; off < 256; off <<= 1) {
            int a = s[t];
            int u = (t >= off) ? s[t - off] : 0;
            __syncthreads();
            s[t] = a + u;
            __syncthreads();
        }
        if (i < N) row_ptr[i] = s[t] - v;
        if (t == 255) blkSum[blockIdx.x] = s[255];
    } else {
        int j = (blockIdx.x - NB) * 256 + t;
        if (j < CH * CP) {
            int k = j / CP, c = j - k * CP;
            w2lp[j] = (c < COUT) ? w2l[k * COUT + c] : 0.0f;
            w2rp[j] = (c < COUT) ? w2r[k * COUT + c] : 0.0f;
        }
        if (j < CP) b2p[j] = (j < COUT) ? b2l[j] : 0.0f;
    }
}

// CSR stage 2b: each block reduces blkSum[0..bid) itself, applies offset.
__global__ __launch_bounds__(256) void scan_apply(int* __restrict__ row_ptr,
        int* __restrict__ cursor, const int* __restrict__ blkSum) {
    __shared__ int s[256];
    int t = threadIdx.x, bid = blockIdx.x;
    int a = 0;
    for (int j = t; j < bid; j += 256) a += blkSum[j];
    s[t] = a;
    __syncthreads();
    for (int off = 128; off > 0; off >>= 1) {
        if (t < off) s[t] += s[t + off];
        __syncthreads();
    }
    int offset = s[0];
    int i = bid * 256 + t;
    if (i < N) {
        int v = row_ptr[i] + offset;
        row_ptr[i] = v;
        cursor[i]  = v;
        if (i == N - 1) row_ptr[N] = E;
    }
}

// CSR stage 3: bucket-fill edge sources
__global__ void fill_kernel(const int* __restrict__ src, const int* __restrict__ dst,
        int* __restrict__ cursor, int* __restrict__ col) {
    int i = blockIdx.x * blockDim.x + threadIdx.x;
    if (i < E) {
        int d = dst[i];
        int p = atomicAdd(&cursor[d], 1);
        col[p] = src[i];
    }
}

// ---------------------------------------------------------------------------
// gather1: agg1[n] = mean_{s in N(n)} x[s]
__global__ __launch_bounds__(128) void gather1_kernel(const float* __restrict__ x,
        const int* __restrict__ row_ptr, const int* __restrict__ col,
        float* __restrict__ agg1) {
    int f = threadIdx.x;
    int base = blockIdx.x * 8;
    if (f >= CIN) return;
    for (int r = 0; r < 8; ++r) {
        int n = base + r;
        int b = row_ptr[n], e = row_ptr[n + 1];
        float inv = 1.0f / (float)max(e - b, 1);
        float a0 = 0.f, a1 = 0.f, a2 = 0.f, a3 = 0.f;
        int j = b;
        for (; j + 3 < e; j += 4) {
            int s0 = col[j], s1 = col[j + 1], s2 = col[j + 2], s3 = col[j + 3];
            a0 += x[s0 * CIN + f];
            a1 += x[s1 * CIN + f];
            a2 += x[s2 * CIN + f];
            a3 += x[s3 * CIN + f];
        }
        for (; j < e; ++j) a0 += x[col[j] * CIN + f];
        agg1[n * CIN + f] = ((a0 + a1) + (a2 + a3)) * inv;
    }
}

// ---------------------------------------------------------------------------
// R10 fused gemm: register-tiled LDS k-loops. R9 post-mortem: inner loop was
// LDS-ISSUE-bound (5 LDS insts per 16 FMAs -> VALUBusy 27%). Now:
//   stage1 (h = agg1@w1l + x@w1r + b1l): lane = (m4 = node-group, cg =
//   ch-group), acc[4][4]; per 4-k group: 4 feature f4 reads (per-lane,
//   fbuf stride 52 -> <=2-way) + 4 weight f4 reads (4-addr broadcast)
//   + 64 FMAs -> 8:1 FMA:LDS-inst (was 3.2:1).
//   stage2: lane = node, 12 ch/wave; per 4-k: 1 hrow f4 (hbuf stride 132,
//   16B aligned) + 12 broadcast weight f4 + 48 FMAs.
// k chunks padded to multiples of 4 with zeros (exact). LDS 59KB -> 2 blk/CU.
__global__ __launch_bounds__(512) void fused_gemm(
        const float* __restrict__ agg1, const float* __restrict__ x,
        const float* __restrict__ w1l, const float* __restrict__ b1l,
        const float* __restrict__ w1r,
        const float* __restrict__ w2lp, const float* __restrict__ b2p,
        const float* __restrict__ w2rp,
        float* __restrict__ gsrc, float* __restrict__ gself) {
    __shared__ float lds[64 * 132 + 52 * CH];   // hbuf (fbuf alias) | wbuf
    float* hbuf = lds;                  // stride 132 (33 f4)
    float* wbuf = lds + 64 * 132;       // 6656 floats
    float4* fbuf4 = (float4*)lds;       // stride 13 f4 (52 floats), dead pre-hbuf
    float4* wbuf4 = (float4*)wbuf;

    int t = threadIdx.x;
    int base = blockIdx.x * 64;
    int lane = t & 63;
    int wv = __builtin_amdgcn_readfirstlane(t >> 6);   // 0..7
    int m4 = lane & 15;
    int cg = lane >> 4;                 // 0..3
    int nmax = N - 1 - base; if (nmax > 63) nmax = 63;

    float acc[4][4];
    #pragma unroll
    for (int im = 0; im < 4; ++im)
        #pragma unroll
        for (int ic = 0; ic < 4; ++ic) acc[im][ic] = b1l[wv * 16 + cg * 4 + ic];

    // ---- stage 1: 2 phases x 2 k-chunks of 52 (k>=100 zero-padded)
    const int wcol = wv * 4 + cg;       // f4 index of this lane's channel slice
    for (int ph = 0; ph < 2; ++ph) {
        const float* F = ph ? x : agg1;
        const float* W = ph ? w1r : w1l;
        for (int k0 = 0; k0 < CIN; k0 += 52) {
            for (int i = t; i < 64 * 13; i += 512) {      // fbuf: 64 rows x 13 f4
                int row = i / 13, j = i - row * 13;
                int rr = row <= nmax ? row : nmax;
                int kk = k0 + j * 4;
                float4 v = make_float4(0.f, 0.f, 0.f, 0.f);
                if (kk < CIN)
                    v = *(const float4*)(F + (size_t)(base + rr) * CIN + kk);
                fbuf4[row * 13 + j] = v;
            }
            for (int i = t; i < 52 * 32; i += 512) {      // wbuf: 52 k x 32 f4
                int k = i >> 5, j = i & 31;
                int kk = k0 + k;
                float4 v = make_float4(0.f, 0.f, 0.f, 0.f);
                if (kk < CIN)
                    v = *(const float4*)(W + (size_t)kk * CH + j * 4);
                wbuf4[i] = v;
            }
            __syncthreads();
            for (int kg = 0; kg < 13; ++kg) {
                float4 f[4];
                f[0] = fbuf4[(m4)      * 13 + kg];
                f[1] = fbuf4[(m4 + 16) * 13 + kg];
                f[2] = fbuf4[(m4 + 32) * 13 + kg];
                f[3] = fbuf4[(m4 + 48) * 13 + kg];
                float4 w0 = wbuf4[(kg * 4 + 0) * 32 + wcol];
                float4 w1 = wbuf4[(kg * 4 + 1) * 32 + wcol];
                float4 w2 = wbuf4[(kg * 4 + 2) * 32 + wcol];
                float4 w3 = wbuf4[(kg * 4 + 3) * 32 + wcol];
                #pragma unroll
                for (int im = 0; im < 4; ++im) {
                    acc[im][0] = fmaf(f[im].x, w0.x, acc[im][0]);
                    acc[im][1] = fmaf(f[im].x, w0.y, acc[im][1]);
                    acc[im][2] = fmaf(f[im].x, w0.z, acc[im][2]);
                    acc[im][3] = fmaf(f[im].x, w0.w, acc[im][3]);
                    acc[im][0] = fmaf(f[im].y, w1.x, acc[im][0]);
                    acc[im][1] = fmaf(f[im].y, w1.y, acc[im][1]);
                    acc[im][2] = fmaf(f[im].y, w1.z, acc[im][2]);
                    acc[im][3] = fmaf(f[im].y, w1.w, acc[im][3]);
                    acc[im][0] = fmaf(f[im].z, w2.x, acc[im][0]);
                    acc[im][1] = fmaf(f[im].z, w2.y, acc[im][1]);
                    acc[im][2] = fmaf(f[im].z, w2.z, acc[im][2]);
                    acc[im][3] = fmaf(f[im].z, w2.w, acc[im][3]);
                    acc[im][0] = fmaf(f[im].w, w3.x, acc[im][0]);
                    acc[im][1] = fmaf(f[im].w, w3.y, acc[im][1]);
                    acc[im][2] = fmaf(f[im].w, w3.z, acc[im][2]);
                    acc[im][3] = fmaf(f[im].w, w3.w, acc[im][3]);
                }
            }
            __syncthreads();
        }
    }
    // spill h tile to LDS (fbuf dead)
    float4* hbuf4 = (float4*)hbuf;
    #pragma unroll
    for (int im = 0; im < 4; ++im)
        hbuf4[(m4 + 16 * im) * 33 + wcol] =
            make_float4(acc[im][0], acc[im][1], acc[im][2], acc[im][3]);
    __syncthreads();

    // ---- stage 2: gsrc/gself from hbuf; w2 slabs per 64-k chunk
    bool isSelf = (wv >= 4);
    bool active = !isSelf || (base < NOUT);
    int d0 = (wv & 3) * 12;
    float a2[12];
    #pragma unroll
    for (int c = 0; c < 12; ++c) a2[c] = isSelf ? b2p[d0 + c] : 0.0f;
    for (int k0 = 0; k0 < CH; k0 += 64) {
        for (int i = t; i < 1536; i += 512) {   // [w2lp 768 f4 | w2rp 768 f4]
            float4 v;
            if (i < 768) v = *(const float4*)(w2lp + (size_t)k0 * CP + i * 4);
            else         v = *(const float4*)(w2rp + (size_t)k0 * CP + (i - 768) * 4);
            wbuf4[i] = v;
        }
        __syncthreads();
        if (active) {
            const float4* hrow4 = (const float4*)(hbuf + lane * 132 + k0);
            const float4* wb4 = wbuf4 + (isSelf ? 768 : 0) + (d0 >> 2);
            for (int kg = 0; kg < 16; ++kg) {
                float4 hv = hrow4[kg];
                const float4* wr = wb4 + kg * 48;   // 12 f4 per k row
                #pragma unroll
                for (int ik = 0; ik < 4; ++ik) {
                    float hk = (ik == 0) ? hv.x : (ik == 1) ? hv.y
                             : (ik == 2) ? hv.z : hv.w;
                    float4 q0 = wr[ik * 12 + 0];
                    float4 q1 = wr[ik * 12 + 1];
                    float4 q2 = wr[ik * 12 + 2];
                    a2[0] = fmaf(hk, q0.x, a2[0]);
                    a2[1] = fmaf(hk, q0.y, a2[1]);
                    a2[2] = fmaf(hk, q0.z, a2[2]);
                    a2[3] = fmaf(hk, q0.w, a2[3]);
                    a2[4] = fmaf(hk, q1.x, a2[4]);
                    a2[5] = fmaf(hk, q1.y, a2[5]);
                    a2[6] = fmaf(hk, q1.z, a2[6]);
                    a2[7] = fmaf(hk, q1.w, a2[7]);
                    a2[8]  = fmaf(hk, q2.x, a2[8]);
                    a2[9]  = fmaf(hk, q2.y, a2[9]);
                    a2[10] = fmaf(hk, q2.z, a2[10]);
                    a2[11] = fmaf(hk, q2.w, a2[11]);
                }
            }
        }
        __syncthreads();
    }
    int n = base + lane;
    if (isSelf) {
        if (n < NOUT) {
            float* G = gself + (size_t)n * CP + d0;
            *(float4*)(G + 0) = make_float4(a2[0], a2[1], a2[2],  a2[3]);
            *(float4*)(G + 4) = make_float4(a2[4], a2[5], a2[6],  a2[7]);
            *(float4*)(G + 8) = make_float4(a2[8], a2[9], a2[10], a2[11]);
        }
    } else if (n < N) {
        float* G = gsrc + (size_t)n * CP + d0;
        *(float4*)(G + 0) = make_float4(a2[0], a2[1], a2[2],  a2[3]);
        *(float4*)(G + 4) = make_float4(a2[4], a2[5], a2[6],  a2[7]);
        *(float4*)(G + 8) = make_float4(a2[8], a2[9], a2[10], a2[11]);
    }
}

// ---------------------------------------------------------------------------
// final: out[n] = log_softmax( mean_{s in N(n)} gsrc[s] + gself[n] )
__global__ __launch_bounds__(64) void final_kernel(const float* __restrict__ gsrc,
        const float* __restrict__ gself, const int* __restrict__ row_ptr,
        const int* __restrict__ col, float* __restrict__ out) {
    int n = blockIdx.x;
    int c = threadIdx.x;
    int b = row_ptr[n], e = row_ptr[n + 1];
    float inv = 1.0f / (float)max(e - b, 1);
    float a0 = 0.f, a1 = 0.f;
    if (c < CP) {
        int j = b;
        for (; j + 1 < e; j += 2) {
            a0 += gsrc[(size_t)col[j] * CP + c];
            a1 += gsrc[(size_t)col[j + 1] * CP + c];
        }
        if (j < e) a0 += gsrc[(size_t)col[j] * CP + c];
    }
    float val = (c < COUT) ? ((a0 + a1) * inv + gself[(size_t)n * CP + c]) : -INFINITY;
    float m = val;
    #pragma unroll
    for (int off = 32; off > 0; off >>= 1) m = fmaxf(m, __shfl_xor(m, off, 64));
    float ex = (c < COUT) ? expf(val - m) : 0.f;
    float ssum = ex;
    #pragma unroll
    for (int off = 32; off > 0; off >>= 1) ssum += __shfl_xor(ssum, off, 64);
    if (c < COUT) out[(size_t)n * COUT + c] = val - m - logf(ssum);
}

// ---------------------------------------------------------------------------
extern "C" void kernel_launch(void* const* d_in, const int* in_sizes, int n_in,
                              void* d_out, int out_size, void* d_ws, size_t ws_size,
                              hipStream_t stream) {
    const float* x   = (const float*)d_in[0];
    const int*   ei  = (const int*)d_in[1];   // [2, E]: row 0 = src, row 1 = dst
    const int*   src = ei;
    const int*   dst = ei + E;
    const float* w1l = (const float*)d_in[3];
    const float* b1l = (const float*)d_in[4];
    const float* w1r = (const float*)d_in[5];
    const float* w2l = (const float*)d_in[6];
    const float* b2l = (const float*)d_in[7];
    const float* w2r = (const float*)d_in[8];
    float* out = (float*)d_out;

    // ws: ints [cnt N | row_ptr N+1 | cursor N | blkSum NB | col E]
    // floats [agg1 N*CIN | gsrc N*CP | gself NOUT*CP | w2lp | w2rp | b2p]
    int* cnt     = (int*)d_ws;
    int* row_ptr = cnt + N;
    int* cursor  = row_ptr + N + 1;
    int* blkSum  = cursor + N;
    int* col     = blkSum + NB;
    size_t intWords = (size_t)N + (N + 1) + N + NB + E;
    intWords = (intWords + 3) & ~(size_t)3;
    float* agg1  = (float*)d_ws + intWords;
    float* gsrc  = agg1 + (size_t)N * CIN;
    float* gself = gsrc + (size_t)N * CP;
    float* w2lp  = gself + (size_t)NOUT * CP;
    float* w2rp  = w2lp + CH * CP;
    float* b2p   = w2rp + CH * CP;
    // total ws ~38.3 MB (< 58.6 MB proven available)

    hipMemsetAsync(cnt, 0, (size_t)N * sizeof(int), stream);
    hist_kernel <<<(E + 255) / 256, 256, 0, stream>>>(dst, cnt);
    scan_blocks <<<NB + PADB, 256, 0, stream>>>(cnt, row_ptr, blkSum,
                                                w2l, w2r, b2l, w2lp, w2rp, b2p);
    scan_apply  <<<NB, 256, 0, stream>>>(row_ptr, cursor, blkSum);
    fill_kernel <<<(E + 255) / 256, 256, 0, stream>>>(src, dst, cursor, col);
    gather1_kernel<<<N / 8, 128, 0, stream>>>(x, row_ptr, col, agg1);
    fused_gemm  <<<(N + 63) / 64, 512, 0, stream>>>(agg1, x, w1l, b1l, w1r,
                                                    w2lp, b2p, w2rp, gsrc, gself);
    final_kernel<<<NOUT, 64, 0, stream>>>(gsrc, gself, row_ptr, col, out);
}

// Round 11
// 312.050 us; speedup vs baseline: 1.2522x; 1.1206x over previous
//
#include <hip/hip_runtime.h>
#include <math.h>

// Problem constants (from reference setup_inputs)
constexpr int N    = 50000;   // nodes
constexpr int E    = 800000;  // edges
constexpr int CIN  = 100;     // input channels
constexpr int CH   = 128;     // hidden channels
constexpr int COUT = 47;      // output channels
constexpr int NOUT = 25000;   // original_size (rows emitted)
constexpr int CP   = 48;      // COUT padded (storage stride)
constexpr int NB   = (N + 255) / 256;        // 196 scan blocks
constexpr int PADB = (CH * 128 + 255) / 256; // 64 pad blocks for w2cat
constexpr int TN   = 128;                    // gemm tile nodes
constexpr int NT   = (N + TN - 1) / TN;      // 391 gemm blocks
constexpr int HS4  = 33;  // hbuf stride in float4 (132 floats, bank-spread 4)
constexpr int FS4  = 9;   // fbuf stride in float4 (36 floats, bank-spread 4)

// ---------------------------------------------------------------------------
// CSR stage 1: in-degree histogram
__global__ void hist_kernel(const int* __restrict__ dst, int* __restrict__ cnt) {
    int i = blockIdx.x * blockDim.x + threadIdx.x;
    if (i < E) atomicAdd(&cnt[dst[i]], 1);
}

// CSR stage 2a: per-block exclusive scan of cnt; extra blocks build the
// concatenated zero-padded layer-2 weights w2cat[k][128] = [w2l|0|w2r|0], b2cat.
__global__ __launch_bounds__(256) void scan_blocks(const int* __restrict__ cnt,
        int* __restrict__ row_ptr, int* __restrict__ blkSum,
        const float* __restrict__ w2l, const float* __restrict__ w2r,
        const float* __restrict__ b2l, float* __restrict__ w2cat,
        float* __restrict__ b2cat) {
    int t = threadIdx.x;
    if (blockIdx.x < NB) {
        __shared__ int s[256];
        int i = blockIdx.x * 256 + t;
        int v = (i < N) ? cnt[i] : 0;
        s[t] = v;
        __syncthreads();
        for (int off = 1; off < 256; off <<= 1) {
            int a = s[t];
            int u = (t >= off) ? s[t - off] : 0;
            __syncthreads();
            s[t] = a + u;
            __syncthreads();
        }
        if (i < N) row_ptr[i] = s[t] - v;
        if (t == 255) blkSum[blockIdx.x] = s[255];
    } else {
        int j = (blockIdx.x - NB) * 256 + t;
        if (j < CH * 128) {
            int k = j >> 7, c = j & 127;
            float v = 0.0f;
            if (c < COUT)                   v = w2l[k * COUT + c];
            else if (c >= 64 && c < 64 + COUT) v = w2r[k * COUT + (c - 64)];
            w2cat[j] = v;
        }
        if (j < 128) b2cat[j] = (j >= 64 && j < 64 + COUT) ? b2l[j - 64] : 0.0f;
    }
}

// CSR stage 2b: each block reduces blkSum[0..bid) itself, applies offset.
__global__ __launch_bounds__(256) void scan_apply(int* __restrict__ row_ptr,
        int* __restrict__ cursor, const int* __restrict__ blkSum) {
    __shared__ int s[256];
    int t = threadIdx.x, bid = blockIdx.x;
    int a = 0;
    for (int j = t; j < bid; j += 256) a += blkSum[j];
    s[t] = a;
    __syncthreads();
    for (int off = 128; off > 0; off >>= 1) {
        if (t < off) s[t] += s[t + off];
        __syncthreads();
    }
    int offset = s[0];
    int i = bid * 256 + t;
    if (i < N) {
        int v = row_ptr[i] + offset;
        row_ptr[i] = v;
        cursor[i]  = v;
        if (i == N - 1) row_ptr[N] = E;
    }
}

// CSR stage 3: bucket-fill edge sources
__global__ void fill_kernel(const int* __restrict__ src, const int* __restrict__ dst,
        int* __restrict__ cursor, int* __restrict__ col) {
    int i = blockIdx.x * blockDim.x + threadIdx.x;
    if (i < E) {
        int d = dst[i];
        int p = atomicAdd(&cursor[d], 1);
        col[p] = src[i];
    }
}

// ---------------------------------------------------------------------------
// gather1 v2 (R11): half-wave per node; lane l<25 owns features 4l..4l+3 and
// reads the whole 400B row as ONE f4 instruction (was 2 wave-insts of b32).
// Unroll-2 neighbors for MLP. Rows are 400B = 16B-aligned.
__global__ __launch_bounds__(256) void gather1_kernel(const float* __restrict__ x,
        const int* __restrict__ row_ptr, const int* __restrict__ col,
        float* __restrict__ agg1) {
    int t = threadIdx.x;
    int n = blockIdx.x * 8 + (t >> 5);
    int l = t & 31;
    int b = row_ptr[n], e = row_ptr[n + 1];
    float inv = 1.0f / (float)max(e - b, 1);
    if (l >= 25) return;
    const float4* xb = (const float4*)x;
    float4 s0 = make_float4(0.f, 0.f, 0.f, 0.f);
    float4 s1 = make_float4(0.f, 0.f, 0.f, 0.f);
    int j = b;
    for (; j + 1 < e; j += 2) {
        float4 v0 = xb[(size_t)col[j]     * 25 + l];
        float4 v1 = xb[(size_t)col[j + 1] * 25 + l];
        s0.x += v0.x; s0.y += v0.y; s0.z += v0.z; s0.w += v0.w;
        s1.x += v1.x; s1.y += v1.y; s1.z += v1.z; s1.w += v1.w;
    }
    if (j < e) {
        float4 v0 = xb[(size_t)col[j] * 25 + l];
        s0.x += v0.x; s0.y += v0.y; s0.z += v0.z; s0.w += v0.w;
    }
    ((float4*)agg1)[(size_t)n * 25 + l] = make_float4(
        (s0.x + s1.x) * inv, (s0.y + s1.y) * inv,
        (s0.z + s1.z) * inv, (s0.w + s1.w) * inv);
}

// ---------------------------------------------------------------------------
// R11 fused gemm v3. Model from R7/R9/R10 post-mortems: LDS pipe issues ~12cyc
// per wave64 ds_read_b128 (broadcast or not) -> minimize LDS-insts per MAC:
// E = 12(am+ac)/(256*am*ac); square 8x8 tiles give E=0.0117 (R10 s1: 0.0234,
// s2: 0.051). 256thr/4 waves, tile=128 nodes; roles = nodeHalf x chHalf; each
// wave an 8x8 register tile over (node, channel). Stage2 computes padded
// C=128 = [gsrc 48|0pad|gself 48|0pad] keeping all reads f4-aligned; gself
// waves skip compute (not barriers) above NOUT. LDS = 128*132 + 28*128 floats
// = 81,920B exactly -> 2 blocks/CU; grid 391 -> ~all blocks resident.
__global__ __launch_bounds__(256) void fused_gemm(
        const float* __restrict__ agg1, const float* __restrict__ x,
        const float* __restrict__ w1l, const float* __restrict__ b1l,
        const float* __restrict__ w1r,
        const float* __restrict__ w2cat, const float* __restrict__ b2cat,
        float* __restrict__ gsrc, float* __restrict__ gself) {
    __shared__ float lds[TN * 132 + 28 * CH];   // 20480 floats = 81920 B
    float4* hbuf4 = (float4*)lds;               // stride HS4=33 f4
    float4* fbuf4 = (float4*)lds;               // stride FS4=9 f4, dead pre-hbuf
    float4* wbuf4 = (float4*)(lds + TN * 132);  // 3584 floats = 896 f4

    int t = threadIdx.x;
    int base = blockIdx.x * TN;
    int lane = t & 63;
    int wv = __builtin_amdgcn_readfirstlane(t >> 6);  // 0..3
    int nh  = wv & 1;                 // node half (64 nodes)
    int chh = wv >> 1;                // channel half (64 ch)
    int m_l = lane & 7;
    int c_l = lane >> 3;
    int row0 = nh * 64 + m_l;         // +8*im
    int nmax = N - 1 - base; if (nmax > TN - 1) nmax = TN - 1;

    float a[8][8];
    #pragma unroll
    for (int q = 0; q < 8; ++q) {
        float bv = b1l[chh * 64 + c_l * 8 + q];
        #pragma unroll
        for (int im = 0; im < 8; ++im) a[im][q] = bv;
    }

    // ---- stage 1: h = agg1@w1l + x@w1r + b1l ; chunks 28,28,28,16
    for (int ph = 0; ph < 2; ++ph) {
        const float* F = ph ? x : agg1;
        const float* W = ph ? w1r : w1l;
        for (int ci = 0; ci < 4; ++ci) {
            int k0 = ci * 28;
            int kc = (ci == 3) ? 16 : 28;
            int kc4 = kc >> 2;                       // 7 or 4
            for (int i = t; i < TN * kc4; i += 256) {  // features
                int row = i / kc4, j = i - row * kc4;
                int rr = row <= nmax ? row : nmax;
                fbuf4[row * FS4 + j] =
                    *(const float4*)(F + (size_t)(base + rr) * CIN + k0 + j * 4);
            }
            for (int i = t; i < kc * 32; i += 256) {   // weights [k][128]
                int k = i >> 5, jj = i & 31;
                wbuf4[i] = *(const float4*)(W + (size_t)(k0 + k) * CH + jj * 4);
            }
            __syncthreads();
            for (int kg = 0; kg < kc4; ++kg) {
                float4 f[8];
                #pragma unroll
                for (int im = 0; im < 8; ++im)
                    f[im] = fbuf4[(row0 + 8 * im) * FS4 + kg];
                #pragma unroll
                for (int j = 0; j < 4; ++j) {
                    float4 w0 = wbuf4[(kg * 4 + j) * 32 + chh * 16 + c_l * 2 + 0];
                    float4 w1 = wbuf4[(kg * 4 + j) * 32 + chh * 16 + c_l * 2 + 1];
                    #pragma unroll
                    for (int im = 0; im < 8; ++im) {
                        float fv = (j == 0) ? f[im].x : (j == 1) ? f[im].y
                                 : (j == 2) ? f[im].z : f[im].w;
                        a[im][0] = fmaf(fv, w0.x, a[im][0]);
                        a[im][1] = fmaf(fv, w0.y, a[im][1]);
                        a[im][2] = fmaf(fv, w0.z, a[im][2]);
                        a[im][3] = fmaf(fv, w0.w, a[im][3]);
                        a[im][4] = fmaf(fv, w1.x, a[im][4]);
                        a[im][5] = fmaf(fv, w1.y, a[im][5]);
                        a[im][6] = fmaf(fv, w1.z, a[im][6]);
                        a[im][7] = fmaf(fv, w1.w, a[im][7]);
                    }
                }
            }
            __syncthreads();
        }
    }
    // spill h tile into hbuf (fbuf alias dead after barrier above)
    #pragma unroll
    for (int im = 0; im < 8; ++im) {
        hbuf4[(row0 + 8 * im) * HS4 + chh * 16 + c_l * 2 + 0] =
            make_float4(a[im][0], a[im][1], a[im][2], a[im][3]);
        hbuf4[(row0 + 8 * im) * HS4 + chh * 16 + c_l * 2 + 1] =
            make_float4(a[im][4], a[im][5], a[im][6], a[im][7]);
    }
    __syncthreads();

    // ---- stage 2: [gsrc|gself] = h @ w2cat (+ b2cat) ; k-chunks of 16
    #pragma unroll
    for (int q = 0; q < 8; ++q) {
        float bv = b2cat[chh * 64 + c_l * 8 + q];
        #pragma unroll
        for (int im = 0; im < 8; ++im) a[im][q] = bv;
    }
    bool skip = (chh == 1) && (base >= NOUT);
    for (int k0 = 0; k0 < CH; k0 += 16) {
        for (int i = t; i < 512; i += 256)   // 16 k x 32 f4
            wbuf4[i] = *(const float4*)(w2cat + (size_t)(k0 + (i >> 5)) * 128
                                        + (i & 31) * 4);
        __syncthreads();
        if (!skip) {
            for (int kg = 0; kg < 4; ++kg) {
                float4 f[8];
                #pragma unroll
                for (int im = 0; im < 8; ++im)
                    f[im] = hbuf4[(row0 + 8 * im) * HS4 + (k0 >> 2) + kg];
                #pragma unroll
                for (int j = 0; j < 4; ++j) {
                    float4 w0 = wbuf4[(kg * 4 + j) * 32 + chh * 16 + c_l * 2 + 0];
                    float4 w1 = wbuf4[(kg * 4 + j) * 32 + chh * 16 + c_l * 2 + 1];
                    #pragma unroll
                    for (int im = 0; im < 8; ++im) {
                        float fv = (j == 0) ? f[im].x : (j == 1) ? f[im].y
                                 : (j == 2) ? f[im].z : f[im].w;
                        a[im][0] = fmaf(fv, w0.x, a[im][0]);
                        a[im][1] = fmaf(fv, w0.y, a[im][1]);
                        a[im][2] = fmaf(fv, w0.z, a[im][2]);
                        a[im][3] = fmaf(fv, w0.w, a[im][3]);
                        a[im][4] = fmaf(fv, w1.x, a[im][4]);
                        a[im][5] = fmaf(fv, w1.y, a[im][5]);
                        a[im][6] = fmaf(fv, w1.z, a[im][6]);
                        a[im][7] = fmaf(fv, w1.w, a[im][7]);
                    }
                }
            }
        }
        __syncthreads();
    }
    // store real 48 channels (c_l<6); pad cols 48..63 discarded
    if (!skip && c_l < 6) {
        float* G = chh ? gself : gsrc;
        int lim = chh ? NOUT : N;
        #pragma unroll
        for (int im = 0; im < 8; ++im) {
            int n = base + row0 + 8 * im;
            if (n < lim) {
                *(float4*)(G + (size_t)n * CP + c_l * 8) =
                    make_float4(a[im][0], a[im][1], a[im][2], a[im][3]);
                *(float4*)(G + (size_t)n * CP + c_l * 8 + 4) =
                    make_float4(a[im][4], a[im][5], a[im][6], a[im][7]);
            }
        }
    }
}

// ---------------------------------------------------------------------------
// final: out[n] = log_softmax( mean_{s in N(n)} gsrc[s] + gself[n] )
__global__ __launch_bounds__(64) void final_kernel(const float* __restrict__ gsrc,
        const float* __restrict__ gself, const int* __restrict__ row_ptr,
        const int* __restrict__ col, float* __restrict__ out) {
    int n = blockIdx.x;
    int c = threadIdx.x;
    int b = row_ptr[n], e = row_ptr[n + 1];
    float inv = 1.0f / (float)max(e - b, 1);
    float a0 = 0.f, a1 = 0.f;
    if (c < CP) {
        int j = b;
        for (; j + 1 < e; j += 2) {
            a0 += gsrc[(size_t)col[j] * CP + c];
            a1 += gsrc[(size_t)col[j + 1] * CP + c];
        }
        if (j < e) a0 += gsrc[(size_t)col[j] * CP + c];
    }
    float val = (c < COUT) ? ((a0 + a1) * inv + gself[(size_t)n * CP + c]) : -INFINITY;
    float m = val;
    #pragma unroll
    for (int off = 32; off > 0; off >>= 1) m = fmaxf(m, __shfl_xor(m, off, 64));
    float ex = (c < COUT) ? expf(val - m) : 0.f;
    float ssum = ex;
    #pragma unroll
    for (int off = 32; off > 0; off >>= 1) ssum += __shfl_xor(ssum, off, 64);
    if (c < COUT) out[(size_t)n * COUT + c] = val - m - logf(ssum);
}

// ---------------------------------------------------------------------------
extern "C" void kernel_launch(void* const* d_in, const int* in_sizes, int n_in,
                              void* d_out, int out_size, void* d_ws, size_t ws_size,
                              hipStream_t stream) {
    const float* x   = (const float*)d_in[0];
    const int*   ei  = (const int*)d_in[1];   // [2, E]: row 0 = src, row 1 = dst
    const int*   src = ei;
    const int*   dst = ei + E;
    const float* w1l = (const float*)d_in[3];
    const float* b1l = (const float*)d_in[4];
    const float* w1r = (const float*)d_in[5];
    const float* w2l = (const float*)d_in[6];
    const float* b2l = (const float*)d_in[7];
    const float* w2r = (const float*)d_in[8];
    float* out = (float*)d_out;

    // ws: ints [cnt N | row_ptr N+1 | cursor N | blkSum NB | col E]
    // floats [agg1 N*CIN | gsrc N*CP | gself NOUT*CP | w2cat CH*128 | b2cat 128]
    int* cnt     = (int*)d_ws;
    int* row_ptr = cnt + N;
    int* cursor  = row_ptr + N + 1;
    int* blkSum  = cursor + N;
    int* col     = blkSum + NB;
    size_t intWords = (size_t)N + (N + 1) + N + NB + E;
    intWords = (intWords + 3) & ~(size_t)3;
    float* agg1  = (float*)d_ws + intWords;
    float* gsrc  = agg1 + (size_t)N * CIN;
    float* gself = gsrc + (size_t)N * CP;
    float* w2cat = gself + (size_t)NOUT * CP;
    float* b2cat = w2cat + (size_t)CH * 128;
    // total ws ~38.4 MB (< 58.6 MB proven available)

    hipMemsetAsync(cnt, 0, (size_t)N * sizeof(int), stream);
    hist_kernel <<<(E + 255) / 256, 256, 0, stream>>>(dst, cnt);
    scan_blocks <<<NB + PADB, 256, 0, stream>>>(cnt, row_ptr, blkSum,
                                                w2l, w2r, b2l, w2cat, b2cat);
    scan_apply  <<<NB, 256, 0, stream>>>(row_ptr, cursor, blkSum);
    fill_kernel <<<(E + 255) / 256, 256, 0, stream>>>(src, dst, cursor, col);
    gather1_kernel<<<N / 8, 256, 0, stream>>>(x, row_ptr, col, agg1);
    fused_gemm  <<<NT, 256, 0, stream>>>(agg1, x, w1l, b1l, w1r,
                                         w2cat, b2cat, gsrc, gself);
    final_kernel<<<NOUT, 64, 0, stream>>>(gsrc, gself, row_ptr, col, out);
}